// Round 11
// baseline (126.308 us; speedup 1.0000x reference)
//
#include <hip/hip_runtime.h>

#define B_ 2
#define T_ 2048
#define C_ 1024
#define H_ 16
#define D_ 64

using bf16x8 = __attribute__((ext_vector_type(8))) short;
using f32x4  = __attribute__((ext_vector_type(4))) float;

static __device__ __forceinline__ short f2bf(float f) {
  unsigned u = __builtin_bit_cast(unsigned, f);
  unsigned r = u + 0x7fffu + ((u >> 16) & 1u);
  return (short)(r >> 16);
}

#define GLD16(gp, lp) __builtin_amdgcn_global_load_lds( \
    (const __attribute__((address_space(1))) void*)(gp), \
    (__attribute__((address_space(3))) void*)(lp), 16, 0, 0)

// ---------------- cast f32 -> bf16 (vectorized) ----------------
__global__ __launch_bounds__(256) void cast_f32_bf16(const float* __restrict__ in,
                                                     short* __restrict__ out) {
  int i = blockIdx.x * blockDim.x + threadIdx.x;
  float4 v = ((const float4*)in)[i];
  short4 o;
  o.x = f2bf(v.x); o.y = f2bf(v.y); o.z = f2bf(v.z); o.w = f2bf(v.w);
  ((short4*)out)[i] = o;
}

// ---------------- transpose + cast: in [R][N] f32 -> out [N][R] bf16 ----------------
__global__ __launch_bounds__(256) void transpose_cast(const float* __restrict__ in,
                                                      short* __restrict__ out,
                                                      int R, int N) {
  __shared__ float tile[32][33];
  int bx = blockIdx.x * 32, by = blockIdx.y * 32;
  int tx = threadIdx.x, ty = threadIdx.y;
  #pragma unroll
  for (int j = 0; j < 32; j += 8)
    tile[ty + j][tx] = in[(size_t)(by + ty + j) * N + bx + tx];
  __syncthreads();
  #pragma unroll
  for (int j = 0; j < 32; j += 8)
    out[(size_t)(bx + ty + j) * R + by + tx] = f2bf(tile[tx][ty + j]);
}

// ---------------- GEMM QKV: 128x128 tile, BK=64, global_load_lds staging ----------------
// Q prescaled by 0.125*log2(e) so attention uses exp2 directly.
__global__ __launch_bounds__(256) void gemm_qkv(const short* __restrict__ A,
                                                const short* __restrict__ Bt,
                                                const float* __restrict__ bias,
                                                short* __restrict__ Qo,
                                                short* __restrict__ Ko,
                                                short* __restrict__ Vo) {
  __shared__ short sA[128 * 64];
  __shared__ short sB[128 * 64];
  const int tid = threadIdx.x;
  const int w = tid >> 6, lane = tid & 63;
  const int wm = w >> 1, wn = w & 1;
  const int g = lane >> 4, r16 = lane & 15;
  const int m0 = blockIdx.x * 128, n0 = blockIdx.y * 128;
  const int krow = lane >> 3, kslot = lane & 7;

  f32x4 acc[4][4] = {};

  for (int k0 = 0; k0 < 1024; k0 += 64) {
    __syncthreads();
    #pragma unroll
    for (int p = 0; p < 4; ++p) {
      int rbase = w * 32 + p * 8;
      int row = rbase + krow;
      GLD16(&A[(size_t)(m0 + row) * 1024 + k0 + ((kslot ^ (row & 7)) * 8)], &sA[rbase * 64]);
      GLD16(&Bt[(size_t)(n0 + row) * 1024 + k0 + ((kslot ^ (row & 7)) * 8)], &sB[rbase * 64]);
    }
    __syncthreads();
    bf16x8 af[4][2], bf[4][2];
    #pragma unroll
    for (int mi = 0; mi < 4; ++mi) {
      int row = wm * 64 + mi * 16 + r16;
      #pragma unroll
      for (int c = 0; c < 2; ++c)
        af[mi][c] = *(const bf16x8*)&sA[row * 64 + (((c * 4 + g) ^ (row & 7)) * 8)];
    }
    #pragma unroll
    for (int ni = 0; ni < 4; ++ni) {
      int row = wn * 64 + ni * 16 + r16;
      #pragma unroll
      for (int c = 0; c < 2; ++c)
        bf[ni][c] = *(const bf16x8*)&sB[row * 64 + (((c * 4 + g) ^ (row & 7)) * 8)];
    }
    __builtin_amdgcn_s_setprio(1);
    #pragma unroll
    for (int mi = 0; mi < 4; ++mi)
      #pragma unroll
      for (int ni = 0; ni < 4; ++ni) {
        acc[mi][ni] = __builtin_amdgcn_mfma_f32_16x16x32_bf16(af[mi][0], bf[ni][0], acc[mi][ni], 0, 0, 0);
        acc[mi][ni] = __builtin_amdgcn_mfma_f32_16x16x32_bf16(af[mi][1], bf[ni][1], acc[mi][ni], 0, 0, 0);
      }
    __builtin_amdgcn_s_setprio(0);
  }

  #pragma unroll
  for (int mi = 0; mi < 4; ++mi) {
    #pragma unroll
    for (int ni = 0; ni < 4; ++ni) {
      int n = n0 + wn * 64 + ni * 16 + r16;
      float bv = bias[n];
      int which = n >> 10;
      int c = n & 1023;
      int hh = c >> 6, d = c & 63;
      short* dst = (which == 0) ? Qo : ((which == 1) ? Ko : Vo);
      float sc = (which == 0) ? 0.18033688f : 1.0f;  // 0.125 * log2(e) folded into Q
      #pragma unroll
      for (int rr = 0; rr < 4; ++rr) {
        int m = m0 + wm * 64 + mi * 16 + g * 4 + rr;
        int b = m >> 11, t = m & 2047;
        dst[(size_t)((b * H_ + hh) * T_ + t) * D_ + d] = f2bf((acc[mi][ni][rr] + bv) * sc);
      }
    }
  }
}

// ---------------- GEMM out: 128x64 tile (512 blocks = 2/CU), BK=64 ----------------
__global__ __launch_bounds__(256) void gemm_out(const short* __restrict__ A,
                                                const short* __restrict__ Bt,
                                                const float* __restrict__ bias,
                                                float* __restrict__ Out) {
  __shared__ short sA[128 * 64];
  __shared__ short sB[64 * 64];
  const int tid = threadIdx.x;
  const int w = tid >> 6, lane = tid & 63;
  const int wm = w >> 1, wn = w & 1;
  const int g = lane >> 4, r16 = lane & 15;
  const int m0 = blockIdx.x * 128, n0 = blockIdx.y * 64;
  const int krow = lane >> 3, kslot = lane & 7;

  f32x4 acc[4][2] = {};

  for (int k0 = 0; k0 < 1024; k0 += 64) {
    __syncthreads();
    #pragma unroll
    for (int p = 0; p < 4; ++p) {
      int rbase = w * 32 + p * 8;
      int row = rbase + krow;
      GLD16(&A[(size_t)(m0 + row) * 1024 + k0 + ((kslot ^ (row & 7)) * 8)], &sA[rbase * 64]);
    }
    #pragma unroll
    for (int p = 0; p < 2; ++p) {
      int rbase = w * 16 + p * 8;
      int row = rbase + krow;
      GLD16(&Bt[(size_t)(n0 + row) * 1024 + k0 + ((kslot ^ (row & 7)) * 8)], &sB[rbase * 64]);
    }
    __syncthreads();
    bf16x8 af[4][2], bf[2][2];
    #pragma unroll
    for (int mi = 0; mi < 4; ++mi) {
      int row = wm * 64 + mi * 16 + r16;
      #pragma unroll
      for (int c = 0; c < 2; ++c)
        af[mi][c] = *(const bf16x8*)&sA[row * 64 + (((c * 4 + g) ^ (row & 7)) * 8)];
    }
    #pragma unroll
    for (int ni = 0; ni < 2; ++ni) {
      int row = wn * 32 + ni * 16 + r16;
      #pragma unroll
      for (int c = 0; c < 2; ++c)
        bf[ni][c] = *(const bf16x8*)&sB[row * 64 + (((c * 4 + g) ^ (row & 7)) * 8)];
    }
    __builtin_amdgcn_s_setprio(1);
    #pragma unroll
    for (int mi = 0; mi < 4; ++mi)
      #pragma unroll
      for (int ni = 0; ni < 2; ++ni) {
        acc[mi][ni] = __builtin_amdgcn_mfma_f32_16x16x32_bf16(af[mi][0], bf[ni][0], acc[mi][ni], 0, 0, 0);
        acc[mi][ni] = __builtin_amdgcn_mfma_f32_16x16x32_bf16(af[mi][1], bf[ni][1], acc[mi][ni], 0, 0, 0);
      }
    __builtin_amdgcn_s_setprio(0);
  }

  #pragma unroll
  for (int mi = 0; mi < 4; ++mi) {
    #pragma unroll
    for (int ni = 0; ni < 2; ++ni) {
      int n = n0 + wn * 32 + ni * 16 + r16;
      float bv = bias[n];
      #pragma unroll
      for (int rr = 0; rr < 4; ++rr) {
        int m = m0 + wm * 64 + mi * 16 + g * 4 + rr;
        Out[(size_t)m * 1024 + n] = acc[mi][ni][rr] + bv;
      }
    }
  }
}

// ---------------- flash attention: 2 waves x 32 q-rows (2 strips), dbuf K+V ----------------
// grid (bh=32, 32); qi = 31 - blockIdx.y (LPT). 128 threads = 2 waves; wave owns rows
// w*32..w*32+31 as 2 strips of 16 sharing every K fragment -> 2 independent softmax
// chains per wave (ILP), K/V LDS reads amortized 2x. 32 KB LDS -> 5 blocks/CU.
// Swapped mfma(K,Q); per-lane partial l; defer-max; packed P feeds PV directly.
__global__ __launch_bounds__(128, 2) void attn_fwd(const short* __restrict__ Q,
                                                   const short* __restrict__ K,
                                                   const short* __restrict__ V,
                                                   short* __restrict__ O) {
  __shared__ short sK[2][64 * 64];   // [key][d], chunk c holds d-chunk c^(key&7)
  __shared__ short vT[2][64 * 64];   // [d][slot], slot = pi(key); chunk c' holds c'^(d&7)

  const int tid = threadIdx.x;
  const int w = tid >> 6, lane = tid & 63;   // w in 0..1
  const int g = lane >> 4, r16 = lane & 15;
  const int bh = blockIdx.x;
  const int b = bh >> 4, hh = bh & 15;
  const int qi = 31 - (int)blockIdx.y;  // LPT: heavy first
  const int q0 = qi * 64;

  const short* Qh = Q + (size_t)bh * T_ * D_;
  const short* Kh = K + (size_t)bh * T_ * D_;
  const short* Vh = V + (size_t)bh * T_ * D_;

  const int krw = lane >> 3, kslot = lane & 7;
  // V slot permutation: slot = a<<5 | c<<3 | b<<2 | d<<1 | e for key = a<<5|b<<4|c<<2|d<<1|e
  const int kp = tid & 31;              // key pair index (keys 2kp, 2kp+1)
  const int vd0 = (tid >> 5) * 8;       // d-group base (0,8,16,24); also +32
  const int vchunk = (kp >> 4) * 4 + ((kp & 7) >> 1);
  const int velem  = ((kp >> 3) & 1) * 4 + 2 * (kp & 1);

  // Q fragments: strips u=0,1 (rows q0 + w*32 + u*16 + r16)
  bf16x8 qf[2][2];
  #pragma unroll
  for (int u = 0; u < 2; ++u) {
    const size_t qoff = (size_t)(q0 + w * 32 + u * 16 + r16) * 64;
    qf[u][0] = *(const bf16x8*)&Qh[qoff + g * 8];
    qf[u][1] = *(const bf16x8*)&Qh[qoff + 32 + g * 8];
  }

  f32x4 o[2][4] = {};
  float m_[2] = {-1e30f, -1e30f}, l_[2] = {0.f, 0.f};  // per-lane partial l

  const int nkt = qi + 1;

  // ---- prologue: stage K(0), V(0) ----
  #pragma unroll
  for (int p = 0; p < 4; ++p) {
    int row = w * 32 + p * 8 + krw;
    GLD16(&Kh[(size_t)row * 64 + ((kslot ^ (row & 7)) * 8)], &sK[0][(w * 32 + p * 8) * 64]);
  }
  {
    int4 va0 = *(const int4*)&Vh[(size_t)(2 * kp) * 64 + vd0];
    int4 va1 = *(const int4*)&Vh[(size_t)(2 * kp + 1) * 64 + vd0];
    int4 vb0_ = *(const int4*)&Vh[(size_t)(2 * kp) * 64 + vd0 + 32];
    int4 vb1_ = *(const int4*)&Vh[(size_t)(2 * kp + 1) * 64 + vd0 + 32];
    const short* a0 = (const short*)&va0; const short* a1 = (const short*)&va1;
    const short* b0 = (const short*)&vb0_; const short* b1 = (const short*)&vb1_;
    #pragma unroll
    for (int j = 0; j < 8; ++j) {
      int d = vd0 + j;  // d&7 == j
      int lo = ((int)(unsigned short)a0[j]) | (((int)(unsigned short)a1[j]) << 16);
      int hi2 = ((int)(unsigned short)b0[j]) | (((int)(unsigned short)b1[j]) << 16);
      *(int*)&vT[0][d * 64 + ((vchunk ^ j) * 8) + velem] = lo;
      *(int*)&vT[0][(d + 32) * 64 + ((vchunk ^ j) * 8) + velem] = hi2;
    }
  }
  __syncthreads();

  for (int kt = 0; kt < nkt; ++kt) {
    const int cur = kt & 1, nxt = cur ^ 1;
    const int k0 = kt * 64;
    const bool pf = (kt + 1 < nkt);

    // ---- issue next-tile staging early (T14) ----
    int4 va0, va1, vb0_, vb1_;
    if (pf) {
      const int k1 = k0 + 64;
      #pragma unroll
      for (int p = 0; p < 4; ++p) {
        int row = w * 32 + p * 8 + krw;
        GLD16(&Kh[(size_t)(k1 + row) * 64 + ((kslot ^ (row & 7)) * 8)],
              &sK[nxt][(w * 32 + p * 8) * 64]);
      }
      va0 = *(const int4*)&Vh[(size_t)(k1 + 2 * kp) * 64 + vd0];
      va1 = *(const int4*)&Vh[(size_t)(k1 + 2 * kp + 1) * 64 + vd0];
      vb0_ = *(const int4*)&Vh[(size_t)(k1 + 2 * kp) * 64 + vd0 + 32];
      vb1_ = *(const int4*)&Vh[(size_t)(k1 + 2 * kp + 1) * 64 + vd0 + 32];
    }

    // ---- S^T = K Q^T for both strips (kf shared) ----
    f32x4 s[2][4] = {};
    __builtin_amdgcn_s_setprio(1);
    #pragma unroll
    for (int nt = 0; nt < 4; ++nt) {
      const int row = nt * 16 + r16;
      const int sw8 = r16 & 7;
      bf16x8 kf0 = *(const bf16x8*)&sK[cur][row * 64 + ((g ^ sw8) * 8)];
      bf16x8 kf1 = *(const bf16x8*)&sK[cur][row * 64 + (((4 + g) ^ sw8) * 8)];
      s[0][nt] = __builtin_amdgcn_mfma_f32_16x16x32_bf16(kf0, qf[0][0], s[0][nt], 0, 0, 0);
      s[0][nt] = __builtin_amdgcn_mfma_f32_16x16x32_bf16(kf1, qf[0][1], s[0][nt], 0, 0, 0);
      s[1][nt] = __builtin_amdgcn_mfma_f32_16x16x32_bf16(kf0, qf[1][0], s[1][nt], 0, 0, 0);
      s[1][nt] = __builtin_amdgcn_mfma_f32_16x16x32_bf16(kf1, qf[1][1], s[1][nt], 0, 0, 0);
    }
    __builtin_amdgcn_s_setprio(0);

    // ---- online softmax per strip (log2 domain; zero cross-lane common path) ----
    bf16x8 pa[2][2];
    #pragma unroll
    for (int u = 0; u < 2; ++u) {
      if (kt == nkt - 1) {  // diagonal tile
        const int qrow = w * 32 + u * 16 + r16;
        #pragma unroll
        for (int nt = 0; nt < 4; ++nt)
          #pragma unroll
          for (int rr = 0; rr < 4; ++rr)
            if (nt * 16 + 4 * g + rr > qrow) s[u][nt][rr] = -1e30f;
      }
      float pmax = s[u][0][0];
      #pragma unroll
      for (int nt = 0; nt < 4; ++nt)
        #pragma unroll
        for (int rr = 0; rr < 4; ++rr)
          pmax = fmaxf(pmax, s[u][nt][rr]);
      if (!__all(pmax - m_[u] <= 8.0f)) {  // defer-max (T13)
        float rmax = fmaxf(pmax, __shfl_xor(pmax, 16));
        rmax = fmaxf(rmax, __shfl_xor(rmax, 32));
        float mn = fmaxf(m_[u], rmax);
        float al = __builtin_amdgcn_exp2f(m_[u] - mn);
        m_[u] = mn;
        l_[u] *= al;
        float av[4];
        #pragma unroll
        for (int rr = 0; rr < 4; ++rr) av[rr] = __shfl(al, 4 * g + rr, 16);
        #pragma unroll
        for (int nt = 0; nt < 4; ++nt)
          #pragma unroll
          for (int rr = 0; rr < 4; ++rr) o[u][nt][rr] *= av[rr];
      }
      float rs = 0.f;
      #pragma unroll
      for (int nt = 0; nt < 4; ++nt)
        #pragma unroll
        for (int rr = 0; rr < 4; ++rr) {
          float p = __builtin_amdgcn_exp2f(s[u][nt][rr] - m_[u]);
          s[u][nt][rr] = p;
          rs += p;
        }
      l_[u] += rs;  // per-lane partial; reduced once in epilogue
      int pk[8];
      #pragma unroll
      for (int nt = 0; nt < 4; ++nt)
        #pragma unroll
        for (int h = 0; h < 2; ++h)
          asm("v_cvt_pk_bf16_f32 %0, %1, %2"
              : "=v"(pk[nt * 2 + h])
              : "v"(s[u][nt][2 * h]), "v"(s[u][nt][2 * h + 1]));
      int4 t0; t0.x = pk[0]; t0.y = pk[1]; t0.z = pk[2]; t0.w = pk[3];
      int4 t1; t1.x = pk[4]; t1.y = pk[5]; t1.z = pk[6]; t1.w = pk[7];
      pa[u][0] = __builtin_bit_cast(bf16x8, t0);
      pa[u][1] = __builtin_bit_cast(bf16x8, t1);
    }

    // ---- O += P @ V for both strips (vb shared) ----
    __builtin_amdgcn_s_setprio(1);
    #pragma unroll
    for (int nt = 0; nt < 4; ++nt) {
      const int d = nt * 16 + r16;
      bf16x8 vb0 = *(const bf16x8*)&vT[cur][d * 64 + ((g ^ (d & 7)) * 8)];
      bf16x8 vb1 = *(const bf16x8*)&vT[cur][d * 64 + (((4 + g) ^ (d & 7)) * 8)];
      o[0][nt] = __builtin_amdgcn_mfma_f32_16x16x32_bf16(pa[0][0], vb0, o[0][nt], 0, 0, 0);
      o[0][nt] = __builtin_amdgcn_mfma_f32_16x16x32_bf16(pa[0][1], vb1, o[0][nt], 0, 0, 0);
      o[1][nt] = __builtin_amdgcn_mfma_f32_16x16x32_bf16(pa[1][0], vb0, o[1][nt], 0, 0, 0);
      o[1][nt] = __builtin_amdgcn_mfma_f32_16x16x32_bf16(pa[1][1], vb1, o[1][nt], 0, 0, 0);
    }
    __builtin_amdgcn_s_setprio(0);

    // ---- late stage-write of V(kt+1) ----
    if (pf) {
      const short* a0 = (const short*)&va0; const short* a1 = (const short*)&va1;
      const short* b0 = (const short*)&vb0_; const short* b1 = (const short*)&vb1_;
      #pragma unroll
      for (int j = 0; j < 8; ++j) {
        int d = vd0 + j;
        int lo = ((int)(unsigned short)a0[j]) | (((int)(unsigned short)a1[j]) << 16);
        int hi2 = ((int)(unsigned short)b0[j]) | (((int)(unsigned short)b1[j]) << 16);
        *(int*)&vT[nxt][d * 64 + ((vchunk ^ j) * 8) + velem] = lo;
        *(int*)&vT[nxt][(d + 32) * 64 + ((vchunk ^ j) * 8) + velem] = hi2;
      }
    }
    __syncthreads();
  }

  // ---- epilogue: reduce per-lane l partials once, then O /= l ----
  #pragma unroll
  for (int u = 0; u < 2; ++u) {
    float lt = l_[u] + __shfl_xor(l_[u], 16);
    lt += __shfl_xor(lt, 32);
    float lv[4];
    #pragma unroll
    for (int rr = 0; rr < 4; ++rr) lv[rr] = __shfl(lt, 4 * g + rr, 16);
    #pragma unroll
    for (int nt = 0; nt < 4; ++nt) {
      int d = nt * 16 + r16;
      #pragma unroll
      for (int rr = 0; rr < 4; ++rr) {
        int t = q0 + w * 32 + u * 16 + 4 * g + rr;
        O[(size_t)(b * T_ + t) * C_ + hh * 64 + d] = f2bf(o[u][nt][rr] / lv[rr]);
      }
    }
  }
}

extern "C" void kernel_launch(void* const* d_in, const int* in_sizes, int n_in,
                              void* d_out, int out_size, void* d_ws, size_t ws_size,
                              hipStream_t stream) {
  const float* x     = (const float*)d_in[0];
  const float* w_qkv = (const float*)d_in[1];
  const float* b_qkv = (const float*)d_in[2];
  const float* w_out = (const float*)d_in[3];
  const float* b_out = (const float*)d_in[4];
  float* out = (float*)d_out;

  char* ws = (char*)d_ws;
  if (ws_size < (size_t)(40u << 20)) return;

  short* xb     = (short*)(ws);                        // 8 MiB  [4096][1024] bf16
  short* wqkvT  = (short*)(ws + ((size_t)8u << 20));   // 6 MiB  [3072][1024] bf16
  short* woutT  = (short*)(ws + ((size_t)14u << 20));  // 2 MiB  [1024][1024] bf16
  short* Qb     = (short*)(ws + ((size_t)16u << 20));  // 8 MiB  [B][H][T][D] (prescaled)
  short* Kb     = (short*)(ws + ((size_t)24u << 20));  // 8 MiB
  short* Vb     = (short*)(ws + ((size_t)32u << 20));  // 8 MiB
  short* attn_o = xb;  // xb dead after gemm_qkv

  cast_f32_bf16<<<4096, 256, 0, stream>>>(x, xb);
  transpose_cast<<<dim3(96, 32), dim3(32, 8), 0, stream>>>(w_qkv, wqkvT, 1024, 3072);
  transpose_cast<<<dim3(32, 32), dim3(32, 8), 0, stream>>>(w_out, woutT, 1024, 1024);
  gemm_qkv<<<dim3(32, 24), 256, 0, stream>>>(xb, wqkvT, b_qkv, Qb, Kb, Vb);
  attn_fwd<<<dim3(32, 32), 128, 0, stream>>>(Qb, Kb, Vb, attn_o);
  gemm_out<<<dim3(32, 16), 256, 0, stream>>>(attn_o, woutT, b_out, out);
}